// Round 10
// baseline (123.066 us; speedup 1.0000x reference)
//
#include <hip/hip_runtime.h>

typedef float f4 __attribute__((ext_vector_type(4)));
typedef float f2 __attribute__((ext_vector_type(2)));

#define N 1536
#define D 768
#define H 64
#define NN (N * N)

// ---------------------------------------------------------------------------
// Kernel 1a: split-K GEMM partials (UNCHANGED - proven numerics).
// ---------------------------------------------------------------------------
__global__ __launch_bounds__(128) void k1_gemm(
    const float* __restrict__ E, const float* __restrict__ pos,
    const float* __restrict__ ppos, const float* __restrict__ W1,
    const float* __restrict__ b1, float* __restrict__ P, int KC)
{
    __shared__ float Es[8][192];

    const int tid = threadIdx.x;
    const int i0  = blockIdx.x * 8;
    const int kcc = blockIdx.y;
    const int k0  = kcc * KC;

    const int hg  = tid & 31;
    const int h0  = hg * 4;
    const int mat = h0 >> 6;
    const int hc  = h0 & 63;
    const int rp  = tid >> 5;
    const float* Wbase = W1 + (size_t)(mat * D + k0) * H + hc;

    f4 acc0 = {0.f, 0.f, 0.f, 0.f};
    f4 acc1 = {0.f, 0.f, 0.f, 0.f};

    for (int ks = 0; ks < KC; ks += 192) {
        if (ks) __syncthreads();
        for (int f = tid; f < 8 * 48; f += 128) {
            int row = f / 48, c = f - row * 48;
            *(f4*)&Es[row][c * 4] =
                *(const f4*)&E[(size_t)(i0 + row) * D + k0 + ks + c * 4];
        }
        __syncthreads();

        const float* Wc  = Wbase + (size_t)ks * H;
        const float* e0p = Es[2 * rp];
        const float* e1p = Es[2 * rp + 1];
        for (int kk = 0; kk < 192; kk += 8) {
#pragma unroll
            for (int u = 0; u < 8; ++u) {
                f4 w = *(const f4*)&Wc[(size_t)(kk + u) * H];
                float e0 = e0p[kk + u], e1 = e1p[kk + u];
                acc0 = __builtin_elementwise_fma((f4){e0, e0, e0, e0}, w, acc0);
                acc1 = __builtin_elementwise_fma((f4){e1, e1, e1, e1}, w, acc1);
            }
        }
    }

    if (kcc == 0) {
        const float* Ws = W1 + (size_t)2 * D * H + hc;
        f4 wp0 = *(const f4*)&Ws[0 * H];
        f4 wp1 = *(const f4*)&Ws[1 * H] + *(const f4*)&Ws[7 * H]; // vdiff fold
        f4 wp2 = *(const f4*)&Ws[2 * H];
        f4 wv0 = *(const f4*)&Ws[4 * H];
        f4 wv1 = *(const f4*)&Ws[5 * H];
        f4 wv2 = *(const f4*)&Ws[6 * H];
        f4 bb  = *(const f4*)&b1[hc];
#pragma unroll
        for (int r = 0; r < 2; ++r) {
            int i = i0 + 2 * rp + r;
            float px = pos[3 * i], py = pos[3 * i + 1], pz = pos[3 * i + 2];
            float vx = px - ppos[3 * i];
            float vy = py - ppos[3 * i + 1];
            float vz = pz - ppos[3 * i + 2];
            f4 g = px * wp0 + py * wp1 + pz * wp2 + vx * wv0 + vy * wv1 + vz * wv2;
            f4 add = (mat == 0) ? (bb - g) : g;
            if (r == 0) acc0 += add; else acc1 += add;
        }
    }

#pragma unroll
    for (int r = 0; r < 2; ++r) {
        int i = i0 + 2 * rp + r;
        f4 a = r ? acc1 : acc0;
#pragma unroll
        for (int c = 0; c < 4; ++c)
            P[(size_t)(kcc * 128 + h0 + c) * N + i] = a[c];
    }
}

// ---------------------------------------------------------------------------
// Kernel 1b: reduce split-K partials (UNCHANGED).
// ---------------------------------------------------------------------------
__global__ __launch_bounds__(256) void k1b_reduce(
    const float* __restrict__ P, float* __restrict__ AB, int nkc)
{
    int idx = blockIdx.x * 256 + threadIdx.x;
    f4 s = {0.f, 0.f, 0.f, 0.f};
    for (int kc = 0; kc < nkc; ++kc)
        s += *(const f4*)&P[(size_t)kc * 128 * N + (size_t)idx * 4];
    *(f4*)&AB[(size_t)idx * 4] = s;
}

// ---------------------------------------------------------------------------
// Kernel 2: 64x64 pair tile, 512 threads (8 waves), 576 blocks.
// 4x staging amortization vs 32x32; 4 blocks/CU x 512 thr = full occupancy.
// Same 8 pairs/thread, identical per-pair numerics/order as R8/R9.
// ---------------------------------------------------------------------------
__global__ __launch_bounds__(512) void k2_main(
    const float* __restrict__ AB, const float* __restrict__ W1,
    const float* __restrict__ W2, const float* __restrict__ b2,
    const float* __restrict__ pos, const float* __restrict__ ppos,
    float* __restrict__ out)
{
    __shared__ float At[16][260];   // [ty][h*4 + a], +4 pad
    __shared__ float Bt[32][130];   // [tx][h*2 + b], +2 pad
    __shared__ float pis[64][3], vis[64][3], pjs[64][3], vjs[64][3];

    const int tid = threadIdx.x;
    const int i0 = blockIdx.y * 64;
    const int j0 = blockIdx.x * 64;

    // ---- staging (transposing writes), ONE barrier total ----
#pragma unroll
    for (int g = 0; g < 2; ++g) {
        int f = g * 512 + tid;          // 0..1023
        int h = f >> 4, c = f & 15;
        f4 va = *(const f4*)&AB[(size_t)h * N + i0 + c * 4];
        *(f4*)&At[c][h * 4] = va;
        f4 vb = *(const f4*)&AB[(size_t)(64 + h) * N + j0 + c * 4];
        *(f2*)&Bt[2 * c][h * 2]     = (f2){vb.x, vb.y};
        *(f2*)&Bt[2 * c + 1][h * 2] = (f2){vb.z, vb.w};
    }
    if (tid < 64) {
        int i = i0 + tid;
        float px = pos[3 * i], py = pos[3 * i + 1], pz = pos[3 * i + 2];
        pis[tid][0] = px; pis[tid][1] = py; pis[tid][2] = pz;
        vis[tid][0] = px - ppos[3 * i];
        vis[tid][1] = py - ppos[3 * i + 1];
        vis[tid][2] = pz - ppos[3 * i + 2];
    } else if (tid < 128) {
        int t = tid - 64;
        int j = j0 + t;
        float px = pos[3 * j], py = pos[3 * j + 1], pz = pos[3 * j + 2];
        pjs[t][0] = px; pjs[t][1] = py; pjs[t][2] = pz;
        vjs[t][0] = px - ppos[3 * j];
        vjs[t][1] = py - ppos[3 * j + 1];
        vjs[t][2] = pz - ppos[3 * j + 2];
    }
    __syncthreads();

    const int tx = tid & 31;   // j: tx*2 + 0..1
    const int ty = tid >> 5;   // i: ty*4 + 0..3  (ty in 0..15)

    // ---- geometry (registers; numpy op order, threshold-sensitive) ----
    f2 dd[4], dyv[4], clv[4];
    {
#pragma clang fp contract(off)
#pragma unroll
        for (int a = 0; a < 4; ++a) {
#pragma unroll
            for (int b = 0; b < 2; ++b) {
                int il = ty * 4 + a, jl = tx * 2 + b;
                float dx = pjs[jl][0] - pis[il][0];
                float dy = pjs[jl][1] - pis[il][1];
                float dz = pjs[jl][2] - pis[il][2];
                float s = dx * dx;
                s = s + dy * dy;
                s = s + dz * dz;
                float d = sqrtf(s);
                float rvx = vjs[jl][0] - vis[il][0];
                float rvy = vjs[jl][1] - vis[il][1];
                float rvz = vjs[jl][2] - vis[il][2];
                float dot = dx * rvx;
                dot = dot + dy * rvy;
                dot = dot + dz * rvz;
                float cl = -dot / fmaxf(d, 1e-6f);
                dd[a][b] = d; dyv[a][b] = dy; clv[a][b] = cl;
            }
        }
    }

    // ---- MLP inner loop: 2 h per window, immediate-offset DS reads ----
    f2 acc[4][4];
#pragma unroll
    for (int a = 0; a < 4; ++a)
#pragma unroll
        for (int l = 0; l < 4; ++l)
            acc[a][l] = (f2){0.f, 0.f};

    const float* w3p = W1 + (size_t)(2 * D + 3) * H;   // uniform

#pragma unroll 4
    for (int hh = 0; hh < 32; ++hh) {
        const int h = hh * 2;
        f4 A0 = *(const f4*)&At[ty][h * 4];
        f4 A1 = *(const f4*)&At[ty][h * 4 + 4];
        f4 Bp = *(const f4*)&Bt[tx][h * 2];       // B for h and h+1
        float w30 = w3p[h], w31 = w3p[h + 1];
        f4 w2a = *(const f4*)&W2[h * 4];
        f4 w2b = *(const f4*)&W2[h * 4 + 4];

        f2 B20 = (f2){Bp.x, Bp.y};
        f2 B21 = (f2){Bp.z, Bp.w};
        f2 w3v0 = (f2){w30, w30};
        f2 w3v1 = (f2){w31, w31};
#pragma unroll
        for (int a = 0; a < 4; ++a) {
            {   // h
                f2 pre = (f2){A0[a], A0[a]} + B20;
                f2 hid = __builtin_elementwise_fma(dd[a], w3v0, pre);
                hid = __builtin_elementwise_max(hid, (f2){0.f, 0.f});
                acc[a][0] = __builtin_elementwise_fma(hid, (f2){w2a.x, w2a.x}, acc[a][0]);
                acc[a][1] = __builtin_elementwise_fma(hid, (f2){w2a.y, w2a.y}, acc[a][1]);
                acc[a][2] = __builtin_elementwise_fma(hid, (f2){w2a.z, w2a.z}, acc[a][2]);
                acc[a][3] = __builtin_elementwise_fma(hid, (f2){w2a.w, w2a.w}, acc[a][3]);
            }
            {   // h+1
                f2 pre = (f2){A1[a], A1[a]} + B21;
                f2 hid = __builtin_elementwise_fma(dd[a], w3v1, pre);
                hid = __builtin_elementwise_max(hid, (f2){0.f, 0.f});
                acc[a][0] = __builtin_elementwise_fma(hid, (f2){w2b.x, w2b.x}, acc[a][0]);
                acc[a][1] = __builtin_elementwise_fma(hid, (f2){w2b.y, w2b.y}, acc[a][1]);
                acc[a][2] = __builtin_elementwise_fma(hid, (f2){w2b.z, w2b.z}, acc[a][2]);
                acc[a][3] = __builtin_elementwise_fma(hid, (f2){w2b.w, w2b.w}, acc[a][3]);
            }
        }
    }

    // ---- epilogue: fast exp/rcp (R9-proven) ----
    const f4 B2v = *(const f4*)b2;

#pragma unroll
    for (int a = 0; a < 4; ++a) {
        int i = i0 + ty * 4 + a;
        f2 rt2, cf2, vl2;
#pragma unroll
        for (int b = 0; b < 2; ++b) {
            int j = j0 + tx * 2 + b;
            float l0 = acc[a][0][b] + B2v.x;
            float l1 = acc[a][1][b] + B2v.y;
            float l2 = acc[a][2][b] + B2v.z;
            float l3 = acc[a][3][b] + B2v.w;
            float mx = l0; int bidx = 0;
            if (l1 > mx) { mx = l1; bidx = 1; }
            if (l2 > mx) { mx = l2; bidx = 2; }
            if (l3 > mx) { mx = l3; bidx = 3; }
            float s = __expf(l0 - mx);
            s += __expf(l1 - mx);
            s += __expf(l2 - mx);
            s += __expf(l3 - mx);
            float conf = __builtin_amdgcn_rcpf(s);   // == max softmax prob

            float d  = dd[a][b];
            float dy = dyv[a][b];
            float cl = clv[a][b];
            bool near = d < 0.25f;
            bool appr = !near && (cl > 0.05f);
            bool flee = !near && !appr && (cl < -0.05f);
            bool above = !near && !appr && !flee && (fabsf(dy) > 0.3f) && (d < 0.5f);
            int rt = near ? 0 : appr ? 1 : flee ? 2 : above ? 3 : bidx;
            float co = near  ? fmaxf(conf, 0.8f)
                     : appr  ? fmaxf(conf, 0.6f)
                     : flee  ? fmaxf(conf, 0.6f)
                     : above ? fmaxf(conf, 0.5f)
                             : conf;
            float vd = ((j > i) && (co > 0.3f)) ? 1.0f : 0.0f;
            rt2[b] = (float)rt;
            cf2[b] = co;
            vl2[b] = vd;
        }
        int col = j0 + tx * 2;
        *(f2*)&out[(size_t)i * N + col]                  = rt2;
        *(f2*)&out[(size_t)NN + (size_t)i * N + col]     = cf2;
        *(f2*)&out[(size_t)2 * NN + (size_t)i * N + col] = vl2;
    }
}

extern "C" void kernel_launch(void* const* d_in, const int* in_sizes, int n_in,
                              void* d_out, int out_size, void* d_ws, size_t ws_size,
                              hipStream_t stream)
{
    const float* E    = (const float*)d_in[0];   // N x 768
    const float* pos  = (const float*)d_in[1];   // N x 3
    const float* ppos = (const float*)d_in[2];   // N x 3
    const float* W1   = (const float*)d_in[3];   // 1544 x 64
    const float* b1   = (const float*)d_in[4];   // 64
    const float* W2   = (const float*)d_in[5];   // 64 x 4
    const float* b2   = (const float*)d_in[6];   // 4
    float* out = (float*)d_out;
    float* P   = (float*)d_ws;

    const size_t part_sz = (size_t)4 * 128 * N;            // floats
    const size_t ab_sz   = (size_t)128 * N;                // floats
    int nkc = (ws_size >= (part_sz + ab_sz) * sizeof(float)) ? 4 : 1;
    int KC  = D / nkc;

    dim3 g1(N / 8, nkc);
    k1_gemm<<<g1, 128, 0, stream>>>(E, pos, ppos, W1, b1, P, KC);

    const float* AB;
    if (nkc > 1) {
        float* ABw = P + part_sz;
        k1b_reduce<<<(128 * N / 4) / 256, 256, 0, stream>>>(P, ABw, nkc);
        AB = ABw;
    } else {
        AB = P;
    }

    dim3 g2(N / 64, N / 64);
    k2_main<<<g2, 512, 0, stream>>>(AB, W1, W2, b2, pos, ppos, out);
}